// Round 1
// baseline (798.690 us; speedup 1.0000x reference)
//
#include <hip/hip_runtime.h>
#include <math.h>

// Problem constants (from reference)
static constexpr int F = 128;    // input/hidden channels per head
static constexpr int H = 4;      // heads
static constexpr int HF = 512;   // H * F
static constexpr int LAYERS = 4;

// ---------------------------------------------------------------------------
// CSR build kernels (counting sort of edges by dst)
// ---------------------------------------------------------------------------
__global__ void hist_kernel(const int* __restrict__ dst, int* __restrict__ deg, int E) {
    int e = blockIdx.x * blockDim.x + threadIdx.x;
    if (e < E) atomicAdd(&deg[dst[e]], 1);
}

__global__ void scan_kernel(const int* __restrict__ deg, int* __restrict__ row_ptr, int n) {
    __shared__ int buf[1024];
    __shared__ int carry;
    if (threadIdx.x == 0) { carry = 0; row_ptr[0] = 0; }
    __syncthreads();
    for (int base = 0; base < n; base += 1024) {
        int i = base + threadIdx.x;
        int v = (i < n) ? deg[i] : 0;
        buf[threadIdx.x] = v;
        __syncthreads();
        for (int off = 1; off < 1024; off <<= 1) {
            int t = (threadIdx.x >= off) ? buf[threadIdx.x - off] : 0;
            __syncthreads();
            buf[threadIdx.x] += t;
            __syncthreads();
        }
        int incl = buf[threadIdx.x];
        if (i < n) row_ptr[i + 1] = carry + incl;
        __syncthreads();
        if (threadIdx.x == 1023) carry += buf[1023];
        __syncthreads();
    }
}

__global__ void scatter_kernel(const int* __restrict__ src, const int* __restrict__ dst,
                               const int* __restrict__ row_ptr, int* __restrict__ cursor,
                               int* __restrict__ csr_src, int E) {
    int e = blockIdx.x * blockDim.x + threadIdx.x;
    if (e < E) {
        int d = dst[e];
        int pos = atomicAdd(&cursor[d], 1);
        csr_src[row_ptr[d] + pos] = src[e];
    }
}

// ---------------------------------------------------------------------------
// Tiled fp32 GEMM: C[M x Ncols] = A[M x 128] @ W[128 x Ncols] + bias
// 64x64 tile, 256 threads, 4x4 microtile, K-chunk 32.
// ---------------------------------------------------------------------------
#define TM 64
#define TN 64
#define KC 32

__global__ __launch_bounds__(256) void gemm128(const float* __restrict__ A,
                                               const float* __restrict__ W,
                                               const float* __restrict__ bias,
                                               float* __restrict__ C,
                                               int M, int Ncols) {
    __shared__ float As[TM][KC + 1];   // [row][k], pitch 33 -> conflict-free broadcast reads
    __shared__ float Ws[KC][TN];       // [k][col], float4-aligned

    const int tid = threadIdx.x;
    const int tx = tid & 15;           // col group 0..15
    const int ty = tid >> 4;           // row group 0..15
    const int row0 = blockIdx.y * TM;
    const int col0 = blockIdx.x * TN;

    float acc[4][4] = {};

    for (int kk = 0; kk < 128; kk += KC) {
        // Load A tile: 64 rows x 32 k; 512 float4 over 256 threads.
#pragma unroll
        for (int j = 0; j < 2; ++j) {
            int f  = tid + j * 256;    // 0..511
            int r  = f >> 3;           // 0..63
            int k4 = f & 7;            // 0..7
            int gr = row0 + r;
            float4 v = make_float4(0.f, 0.f, 0.f, 0.f);
            if (gr < M) v = *(const float4*)(A + gr * 128 + kk + k4 * 4);
            As[r][k4 * 4 + 0] = v.x;
            As[r][k4 * 4 + 1] = v.y;
            As[r][k4 * 4 + 2] = v.z;
            As[r][k4 * 4 + 3] = v.w;
        }
        // Load W tile: 32 k x 64 cols; 512 float4 over 256 threads.
#pragma unroll
        for (int j = 0; j < 2; ++j) {
            int f  = tid + j * 256;
            int c4 = f & 15;           // 0..15
            int k  = f >> 4;           // 0..31
            float4 v = *(const float4*)(W + (kk + k) * Ncols + col0 + c4 * 4);
            *(float4*)&Ws[k][c4 * 4] = v;
        }
        __syncthreads();

#pragma unroll
        for (int k = 0; k < KC; ++k) {
            float a0 = As[ty * 4 + 0][k];
            float a1 = As[ty * 4 + 1][k];
            float a2 = As[ty * 4 + 2][k];
            float a3 = As[ty * 4 + 3][k];
            float4 w = *(const float4*)&Ws[k][tx * 4];
            acc[0][0] += a0 * w.x; acc[0][1] += a0 * w.y; acc[0][2] += a0 * w.z; acc[0][3] += a0 * w.w;
            acc[1][0] += a1 * w.x; acc[1][1] += a1 * w.y; acc[1][2] += a1 * w.z; acc[1][3] += a1 * w.w;
            acc[2][0] += a2 * w.x; acc[2][1] += a2 * w.y; acc[2][2] += a2 * w.z; acc[2][3] += a2 * w.w;
            acc[3][0] += a3 * w.x; acc[3][1] += a3 * w.y; acc[3][2] += a3 * w.z; acc[3][3] += a3 * w.w;
        }
        __syncthreads();
    }

    int gc = col0 + tx * 4;
    float4 b = *(const float4*)(bias + gc);
#pragma unroll
    for (int i = 0; i < 4; ++i) {
        int gr = row0 + ty * 4 + i;
        if (gr < M) {
            float4 o = make_float4(acc[i][0] + b.x, acc[i][1] + b.y,
                                   acc[i][2] + b.z, acc[i][3] + b.w);
            *(float4*)(C + gr * Ncols + gc) = o;
        }
    }
}

// ---------------------------------------------------------------------------
// Attention: one block (256 thr = 4 waves) per destination node.
// Wave h handles head h: online softmax over incoming edges, then head-mean
// + skip (+ReLU) in the epilogue.
// ---------------------------------------------------------------------------
__global__ __launch_bounds__(256) void attn_kernel(const float* __restrict__ Q,
                                                   const float* __restrict__ K,
                                                   const float* __restrict__ V,
                                                   const float* __restrict__ S,
                                                   const int* __restrict__ row_ptr,
                                                   const int* __restrict__ csr_src,
                                                   float* __restrict__ out,
                                                   int relu, int N) {
    const int node = blockIdx.x;
    if (node >= N) return;
    const int h    = threadIdx.x >> 6;   // head = wave id
    const int lane = threadIdx.x & 63;

    const float scale_qk = 0.08838834764831845f;   // 1/sqrt(128)

    float2 qv = *(const float2*)(Q + ((size_t)node * H + h) * F + lane * 2);

    float m = -INFINITY;
    float denom = 0.f;
    float acc0 = 0.f, acc1 = 0.f;

    const int beg = row_ptr[node];
    const int end = row_ptr[node + 1];
    for (int i = beg; i < end; ++i) {
        int s = csr_src[i];
        float2 kv = *(const float2*)(K + ((size_t)s * H + h) * F + lane * 2);
        float p = qv.x * kv.x + qv.y * kv.y;
        // wave-wide sum (butterfly over 64 lanes)
#pragma unroll
        for (int off = 32; off > 0; off >>= 1) p += __shfl_xor(p, off, 64);
        float alpha = p * scale_qk;

        float mn = fmaxf(m, alpha);
        float rescale = __expf(m - mn);      // 0 on first edge (m = -inf)
        float w = __expf(alpha - mn);
        denom = denom * rescale + w;

        float2 vv = *(const float2*)(V + ((size_t)s * H + h) * F + lane * 2);
        acc0 = acc0 * rescale + w * vv.x;
        acc1 = acc1 * rescale + w * vv.y;
        m = mn;
    }

    float inv = (denom > 0.f) ? 1.f / denom : 0.f;
    acc0 *= inv;
    acc1 *= inv;

    __shared__ float sm[H][F];
    sm[h][lane * 2 + 0] = acc0;
    sm[h][lane * 2 + 1] = acc1;
    __syncthreads();

    if (threadIdx.x < F) {
        int c = threadIdx.x;
        float o = 0.25f * (sm[0][c] + sm[1][c] + sm[2][c] + sm[3][c])
                + S[(size_t)node * F + c];
        if (relu) o = fmaxf(o, 0.f);
        out[(size_t)node * F + c] = o;
    }
}

// ---------------------------------------------------------------------------
// Launch
// ---------------------------------------------------------------------------
extern "C" void kernel_launch(void* const* d_in, const int* in_sizes, int n_in,
                              void* d_out, int out_size, void* d_ws, size_t ws_size,
                              hipStream_t stream) {
    const float* x     = (const float*)d_in[0];
    const int*   ei    = (const int*)d_in[1];
    const float* Wq    = (const float*)d_in[2];
    const float* bq    = (const float*)d_in[3];
    const float* Wk    = (const float*)d_in[4];
    const float* bk    = (const float*)d_in[5];
    const float* Wv    = (const float*)d_in[6];
    const float* bv    = (const float*)d_in[7];
    const float* Wskip = (const float*)d_in[8];
    const float* bskip = (const float*)d_in[9];
    float* out = (float*)d_out;

    const int N = in_sizes[0] / F;       // 10000
    const int E = in_sizes[1] / 2;       // 160000

    const int* src = ei;                 // edge_index[0]
    const int* dst = ei + E;             // edge_index[1]

    // Workspace layout (floats then ints)
    float* hbuf0 = (float*)d_ws;
    float* hbuf1 = hbuf0 + (size_t)N * F;
    float* Qb    = hbuf1 + (size_t)N * F;
    float* Kb    = Qb + (size_t)N * HF;
    float* Vb    = Kb + (size_t)N * HF;
    float* Sb    = Vb + (size_t)N * HF;
    int*   deg     = (int*)(Sb + (size_t)N * F);
    int*   cursor  = deg + N;
    int*   row_ptr = cursor + N;
    int*   csr_src = row_ptr + (N + 1);

    // --- CSR build (once per call; edge_index is restored pristine each call)
    hipMemsetAsync(deg, 0, 2 * (size_t)N * sizeof(int), stream);  // deg + cursor
    {
        int blocks = (E + 255) / 256;
        hist_kernel<<<blocks, 256, 0, stream>>>(dst, deg, E);
        scan_kernel<<<1, 1024, 0, stream>>>(deg, row_ptr, N);
        scatter_kernel<<<blocks, 256, 0, stream>>>(src, dst, row_ptr, cursor, csr_src, E);
    }

    const int rowBlocks = (N + TM - 1) / TM;

    const float* h_in = x;
    for (int l = 0; l < LAYERS; ++l) {
        const float* wq = Wq + (size_t)l * 128 * HF;
        const float* bq_l = bq + (size_t)l * HF;
        const float* wk = Wk + (size_t)l * 128 * HF;
        const float* bk_l = bk + (size_t)l * HF;
        const float* wv = Wv + (size_t)l * 128 * HF;
        const float* bv_l = bv + (size_t)l * HF;
        const float* ws_l = Wskip + (size_t)l * 128 * F;
        const float* bs_l = bskip + (size_t)l * F;

        dim3 gridQKV(HF / TN, rowBlocks);
        dim3 gridS(F / TN, rowBlocks);
        gemm128<<<gridQKV, 256, 0, stream>>>(h_in, wq, bq_l, Qb, N, HF);
        gemm128<<<gridQKV, 256, 0, stream>>>(h_in, wk, bk_l, Kb, N, HF);
        gemm128<<<gridQKV, 256, 0, stream>>>(h_in, wv, bv_l, Vb, N, HF);
        gemm128<<<gridS,   256, 0, stream>>>(h_in, ws_l, bs_l, Sb, N, F);

        float* h_out;
        int relu;
        if (l == LAYERS - 1) { h_out = out; relu = 0; }
        else { h_out = (l % 2 == 0) ? hbuf0 : hbuf1; relu = 1; }

        attn_kernel<<<N, 256, 0, stream>>>(Qb, Kb, Vb, Sb, row_ptr, csr_src,
                                           h_out, relu, N);
        h_in = h_out;
    }
}

// Round 2
// 461.325 us; speedup vs baseline: 1.7313x; 1.7313x over previous
//
#include <hip/hip_runtime.h>
#include <math.h>

static constexpr int F  = 128;    // channels per head
static constexpr int H  = 4;      // heads
static constexpr int HF = 512;    // H*F
static constexpr int NC = 1664;   // packed GEMM cols: Q(512)|K(512)|V(512)|S(128)
static constexpr int LAYERS = 4;

typedef __attribute__((ext_vector_type(8))) short bf16x8;   // 8 bf16 (4 VGPRs)
typedef __attribute__((ext_vector_type(4))) float f32x4;

__device__ __forceinline__ unsigned short f2bf(float f) {
    union { float f; unsigned u; } v; v.f = f;
    unsigned r = (v.u + 0x7FFFu + ((v.u >> 16) & 1u)) >> 16;  // RNE
    return (unsigned short)r;
}
__device__ __forceinline__ float bf2f(unsigned short b) {
    union { unsigned u; float f; } v; v.u = ((unsigned)b) << 16;
    return v.f;
}

// ---------------------------------------------------------------------------
// CSR build (counting sort of edges by dst)
// ---------------------------------------------------------------------------
__global__ void hist_kernel(const int* __restrict__ dst, int* __restrict__ deg, int E) {
    int e = blockIdx.x * blockDim.x + threadIdx.x;
    if (e < E) atomicAdd(&deg[dst[e]], 1);
}

__global__ void scan_kernel(const int* __restrict__ deg, int* __restrict__ row_ptr, int n) {
    __shared__ int buf[1024];
    __shared__ int carry;
    if (threadIdx.x == 0) { carry = 0; row_ptr[0] = 0; }
    __syncthreads();
    for (int base = 0; base < n; base += 1024) {
        int i = base + threadIdx.x;
        int v = (i < n) ? deg[i] : 0;
        buf[threadIdx.x] = v;
        __syncthreads();
        for (int off = 1; off < 1024; off <<= 1) {
            int t = (threadIdx.x >= off) ? buf[threadIdx.x - off] : 0;
            __syncthreads();
            buf[threadIdx.x] += t;
            __syncthreads();
        }
        int incl = buf[threadIdx.x];
        if (i < n) row_ptr[i + 1] = carry + incl;
        __syncthreads();
        if (threadIdx.x == 1023) carry += buf[1023];
        __syncthreads();
    }
}

__global__ void scatter_kernel(const int* __restrict__ src, const int* __restrict__ dst,
                               const int* __restrict__ row_ptr, int* __restrict__ cursor,
                               int* __restrict__ csr_src, int E) {
    int e = blockIdx.x * blockDim.x + threadIdx.x;
    if (e < E) {
        int d = dst[e];
        int pos = atomicAdd(&cursor[d], 1);
        csr_src[row_ptr[d] + pos] = src[e];
    }
}

// ---------------------------------------------------------------------------
// fp32 -> bf16 convert (x -> h_bf at layer 0)
// ---------------------------------------------------------------------------
__global__ void convert_kernel(const float* __restrict__ in, unsigned short* __restrict__ out, int n4) {
    int i = blockIdx.x * blockDim.x + threadIdx.x;
    if (i < n4) {
        float4 v = *(const float4*)(in + (size_t)i * 4);
        ushort4 o;
        o.x = f2bf(v.x); o.y = f2bf(v.y); o.z = f2bf(v.z); o.w = f2bf(v.w);
        *(ushort4*)(out + (size_t)i * 4) = o;
    }
}

// ---------------------------------------------------------------------------
// Weight pack: Wt[l][n][k] (bf16, k contiguous) from Wq/Wk/Wv/Wskip (fp32, [k][n])
// n in [0,512)->Wq, [512,1024)->Wk, [1024,1536)->Wv, [1536,1664)->Wskip
// ---------------------------------------------------------------------------
__global__ void pack_w_kernel(const float* __restrict__ Wq, const float* __restrict__ Wk,
                              const float* __restrict__ Wv, const float* __restrict__ Ws,
                              unsigned short* __restrict__ Wt) {
    int idx = blockIdx.x * blockDim.x + threadIdx.x;   // l*128*NC + k*NC + n  (n fastest -> coalesced reads)
    int total = LAYERS * 128 * NC;
    if (idx >= total) return;
    int n = idx % NC;
    int k = (idx / NC) % 128;
    int l = idx / (128 * NC);
    float v;
    if (n < 512)       v = Wq[(size_t)l * 128 * 512 + (size_t)k * 512 + n];
    else if (n < 1024) v = Wk[(size_t)l * 128 * 512 + (size_t)k * 512 + (n - 512)];
    else if (n < 1536) v = Wv[(size_t)l * 128 * 512 + (size_t)k * 512 + (n - 1024)];
    else               v = Ws[(size_t)l * 128 * 128 + (size_t)k * 128 + (n - 1536)];
    Wt[(size_t)l * NC * 128 + (size_t)n * 128 + k] = f2bf(v);
}

__global__ void pack_b_kernel(const float* __restrict__ bq, const float* __restrict__ bk,
                              const float* __restrict__ bv, const float* __restrict__ bs,
                              float* __restrict__ biasP) {
    int idx = blockIdx.x * blockDim.x + threadIdx.x;   // l*NC + n
    if (idx >= LAYERS * NC) return;
    int n = idx % NC;
    int l = idx / NC;
    float v;
    if (n < 512)       v = bq[(size_t)l * 512 + n];
    else if (n < 1024) v = bk[(size_t)l * 512 + (n - 512)];
    else if (n < 1536) v = bv[(size_t)l * 512 + (n - 1024)];
    else               v = bs[(size_t)l * 128 + (n - 1536)];
    biasP[idx] = v;
}

// ---------------------------------------------------------------------------
// Fused bf16 MFMA GEMM: C[M x 1664] = A[M x 128] @ Wt^T + bias
// 128x128 tile, 256 thr = 4 waves (2x2), each wave 64x64 via 4x4 of 16x16x32.
// Epilogue scatters cols into Q/K/V (bf16) and S (fp32).
// ---------------------------------------------------------------------------
__global__ __launch_bounds__(256) void gemm_mfma(
    const unsigned short* __restrict__ Abf,   // [M][128] bf16
    const unsigned short* __restrict__ Wt,    // [NC][128] bf16 (layer base)
    const float* __restrict__ bias,           // [NC]
    unsigned short* __restrict__ Qb,          // [M][512] bf16
    unsigned short* __restrict__ Kb,
    unsigned short* __restrict__ Vb,
    float* __restrict__ Sb,                   // [M][128] fp32
    int M)
{
    __shared__ unsigned short As[128][72];    // 64+8 pad; row pitch 144 B (16B-aligned)
    __shared__ unsigned short Bs[128][72];

    const int tid = threadIdx.x;
    const int wave = tid >> 6, lane = tid & 63;
    const int lane16 = lane & 15, quad = lane >> 4;
    const int wr = wave >> 1, wc = wave & 1;
    const int row0 = blockIdx.y * 128;
    const int col0 = blockIdx.x * 128;

    f32x4 acc[4][4] = {};

    for (int kk = 0; kk < 128; kk += 64) {
        // stage A tile: 128 rows x 64 k (bf16), 1024 x 16B chunks over 256 thr
#pragma unroll
        for (int j = 0; j < 4; ++j) {
            int c = tid + j * 256;
            int r = c >> 3, c8 = (c & 7) * 8;
            bf16x8 v = {};
            if (row0 + r < M) v = *(const bf16x8*)(Abf + (size_t)(row0 + r) * 128 + kk + c8);
            *(bf16x8*)&As[r][c8] = v;
        }
        // stage B tile: 128 n x 64 k
#pragma unroll
        for (int j = 0; j < 4; ++j) {
            int c = tid + j * 256;
            int r = c >> 3, c8 = (c & 7) * 8;
            *(bf16x8*)&Bs[r][c8] = *(const bf16x8*)(Wt + (size_t)(col0 + r) * 128 + kk + c8);
        }
        __syncthreads();

#pragma unroll
        for (int ks = 0; ks < 2; ++ks) {
            bf16x8 a[4], b[4];
#pragma unroll
            for (int i = 0; i < 4; ++i)
                a[i] = *(const bf16x8*)&As[wr * 64 + i * 16 + lane16][ks * 32 + quad * 8];
#pragma unroll
            for (int i = 0; i < 4; ++i)
                b[i] = *(const bf16x8*)&Bs[wc * 64 + i * 16 + lane16][ks * 32 + quad * 8];
#pragma unroll
            for (int mi = 0; mi < 4; ++mi)
#pragma unroll
                for (int ni = 0; ni < 4; ++ni)
                    acc[mi][ni] = __builtin_amdgcn_mfma_f32_16x16x32_bf16(
                        a[mi], b[ni], acc[mi][ni], 0, 0, 0);
        }
        __syncthreads();
    }

    // Epilogue: C/D layout col = lane&15, row = quad*4 + reg
#pragma unroll
    for (int mi = 0; mi < 4; ++mi) {
        int rowb = row0 + wr * 64 + mi * 16 + quad * 4;
#pragma unroll
        for (int ni = 0; ni < 4; ++ni) {
            int col = col0 + wc * 64 + ni * 16 + lane16;
            float bv = bias[col];
#pragma unroll
            for (int r = 0; r < 4; ++r) {
                int gr = rowb + r;
                if (gr < M) {
                    float v = acc[mi][ni][r] + bv;
                    if (col0 < 512)       Qb[(size_t)gr * 512 + col] = f2bf(v);
                    else if (col0 < 1024) Kb[(size_t)gr * 512 + (col - 512)] = f2bf(v);
                    else if (col0 < 1536) Vb[(size_t)gr * 512 + (col - 1024)] = f2bf(v);
                    else                  Sb[(size_t)gr * 128 + (col - 1536)] = v;
                }
            }
        }
    }
}

// ---------------------------------------------------------------------------
// Attention: one block (4 waves = 4 heads) per destination node, bf16 K/V/Q,
// online softmax, edges unrolled x2 to break the exp/rescale chain.
// ---------------------------------------------------------------------------
__global__ __launch_bounds__(256) void attn_kernel(
    const unsigned short* __restrict__ Q,    // [N][512] bf16
    const unsigned short* __restrict__ K,
    const unsigned short* __restrict__ V,
    const float* __restrict__ S,             // [N][128]
    const int* __restrict__ row_ptr,
    const int* __restrict__ csr_src,
    float* __restrict__ out_f,               // final layer (or null)
    unsigned short* __restrict__ out_bf,     // next-layer input (or null)
    int relu, int N)
{
    const int node = blockIdx.x;
    if (node >= N) return;
    const int h = threadIdx.x >> 6;
    const int lane = threadIdx.x & 63;
    const int choff = h * F + lane * 2;       // 2 channels per lane

    const float scale_qk = 0.08838834764831845f;   // 1/sqrt(128)

    unsigned qu = *(const unsigned*)(Q + (size_t)node * HF + choff);
    float q0 = bf2f((unsigned short)(qu & 0xffff));
    float q1 = bf2f((unsigned short)(qu >> 16));

    float m = -INFINITY, denom = 0.f, acc0 = 0.f, acc1 = 0.f;

    const int beg = row_ptr[node];
    const int end = row_ptr[node + 1];
    int i = beg;
    for (; i + 2 <= end; i += 2) {
        int s0 = csr_src[i], s1 = csr_src[i + 1];
        unsigned ku0 = *(const unsigned*)(K + (size_t)s0 * HF + choff);
        unsigned ku1 = *(const unsigned*)(K + (size_t)s1 * HF + choff);
        unsigned vu0 = *(const unsigned*)(V + (size_t)s0 * HF + choff);
        unsigned vu1 = *(const unsigned*)(V + (size_t)s1 * HF + choff);
        float p0 = q0 * bf2f((unsigned short)(ku0 & 0xffff)) + q1 * bf2f((unsigned short)(ku0 >> 16));
        float p1 = q0 * bf2f((unsigned short)(ku1 & 0xffff)) + q1 * bf2f((unsigned short)(ku1 >> 16));
#pragma unroll
        for (int off = 32; off > 0; off >>= 1) {
            p0 += __shfl_xor(p0, off, 64);
            p1 += __shfl_xor(p1, off, 64);
        }
        float a0 = p0 * scale_qk, a1 = p1 * scale_qk;
        float mn = fmaxf(m, fmaxf(a0, a1));
        float rs = __expf(m - mn);            // 0 on first pair (m = -inf)
        float w0 = __expf(a0 - mn), w1 = __expf(a1 - mn);
        denom = denom * rs + w0 + w1;
        acc0 = acc0 * rs + w0 * bf2f((unsigned short)(vu0 & 0xffff)) + w1 * bf2f((unsigned short)(vu1 & 0xffff));
        acc1 = acc1 * rs + w0 * bf2f((unsigned short)(vu0 >> 16)) + w1 * bf2f((unsigned short)(vu1 >> 16));
        m = mn;
    }
    for (; i < end; ++i) {
        int s0 = csr_src[i];
        unsigned ku0 = *(const unsigned*)(K + (size_t)s0 * HF + choff);
        unsigned vu0 = *(const unsigned*)(V + (size_t)s0 * HF + choff);
        float p0 = q0 * bf2f((unsigned short)(ku0 & 0xffff)) + q1 * bf2f((unsigned short)(ku0 >> 16));
#pragma unroll
        for (int off = 32; off > 0; off >>= 1) p0 += __shfl_xor(p0, off, 64);
        float a0 = p0 * scale_qk;
        float mn = fmaxf(m, a0);
        float rs = __expf(m - mn);
        float w0 = __expf(a0 - mn);
        denom = denom * rs + w0;
        acc0 = acc0 * rs + w0 * bf2f((unsigned short)(vu0 & 0xffff));
        acc1 = acc1 * rs + w0 * bf2f((unsigned short)(vu0 >> 16));
        m = mn;
    }

    float inv = (denom > 0.f) ? 1.f / denom : 0.f;

    __shared__ float sm[H][F];
    sm[h][lane * 2 + 0] = acc0 * inv;
    sm[h][lane * 2 + 1] = acc1 * inv;
    __syncthreads();

    if (threadIdx.x < F) {
        int c = threadIdx.x;
        float o = 0.25f * (sm[0][c] + sm[1][c] + sm[2][c] + sm[3][c])
                + S[(size_t)node * F + c];
        if (relu) o = fmaxf(o, 0.f);
        if (out_f)  out_f[(size_t)node * F + c] = o;
        if (out_bf) out_bf[(size_t)node * F + c] = f2bf(o);
    }
}

// ---------------------------------------------------------------------------
// Launch
// ---------------------------------------------------------------------------
extern "C" void kernel_launch(void* const* d_in, const int* in_sizes, int n_in,
                              void* d_out, int out_size, void* d_ws, size_t ws_size,
                              hipStream_t stream) {
    const float* x     = (const float*)d_in[0];
    const int*   ei    = (const int*)d_in[1];
    const float* Wq    = (const float*)d_in[2];
    const float* bq    = (const float*)d_in[3];
    const float* Wk    = (const float*)d_in[4];
    const float* bk    = (const float*)d_in[5];
    const float* Wv    = (const float*)d_in[6];
    const float* bv    = (const float*)d_in[7];
    const float* Wskip = (const float*)d_in[8];
    const float* bskip = (const float*)d_in[9];
    float* out = (float*)d_out;

    const int N = in_sizes[0] / F;       // 10000
    const int E = in_sizes[1] / 2;       // 160000

    const int* src = ei;
    const int* dst = ei + E;

    // Workspace layout (all chunks 256B-aligned by construction)
    char* p = (char*)d_ws;
    float* Sb    = (float*)p;                 p += (size_t)N * F * sizeof(float);
    float* biasP = (float*)p;                 p += (size_t)LAYERS * NC * sizeof(float);
    unsigned short* h_bf = (unsigned short*)p; p += (size_t)N * F * sizeof(unsigned short);
    unsigned short* Qb   = (unsigned short*)p; p += (size_t)N * HF * sizeof(unsigned short);
    unsigned short* Kb   = (unsigned short*)p; p += (size_t)N * HF * sizeof(unsigned short);
    unsigned short* Vb   = (unsigned short*)p; p += (size_t)N * HF * sizeof(unsigned short);
    unsigned short* WtP  = (unsigned short*)p; p += (size_t)LAYERS * NC * 128 * sizeof(unsigned short);
    int* deg     = (int*)p;                   p += (size_t)N * sizeof(int);
    int* cursor  = (int*)p;                   p += (size_t)N * sizeof(int);
    int* row_ptr = (int*)p;                   p += (size_t)(N + 1) * sizeof(int);
    int* csr_src = (int*)p;

    // --- CSR build
    hipMemsetAsync(deg, 0, 2 * (size_t)N * sizeof(int), stream);  // deg + cursor
    {
        int blocks = (E + 255) / 256;
        hist_kernel<<<blocks, 256, 0, stream>>>(dst, deg, E);
        scan_kernel<<<1, 1024, 0, stream>>>(deg, row_ptr, N);
        scatter_kernel<<<blocks, 256, 0, stream>>>(src, dst, row_ptr, cursor, csr_src, E);
    }

    // --- One-time packs/converts
    convert_kernel<<<(N * F / 4 + 255) / 256, 256, 0, stream>>>(x, h_bf, N * F / 4);
    pack_w_kernel<<<(LAYERS * 128 * NC + 255) / 256, 256, 0, stream>>>(Wq, Wk, Wv, Wskip, WtP);
    pack_b_kernel<<<(LAYERS * NC + 255) / 256, 256, 0, stream>>>(bq, bk, bv, bskip, biasP);

    const int rowBlocks = (N + 127) / 128;

    for (int l = 0; l < LAYERS; ++l) {
        dim3 grid(NC / 128, rowBlocks);
        gemm_mfma<<<grid, 256, 0, stream>>>(h_bf,
                                            WtP + (size_t)l * NC * 128,
                                            biasP + (size_t)l * NC,
                                            Qb, Kb, Vb, Sb, N);

        float* out_f = nullptr;
        unsigned short* out_bf = nullptr;
        int relu;
        if (l == LAYERS - 1) { out_f = out; relu = 0; }
        else { out_bf = h_bf; relu = 1; }

        attn_kernel<<<N, 256, 0, stream>>>(Qb, Kb, Vb, Sb, row_ptr, csr_src,
                                           out_f, out_bf, relu, N);
    }
}